// Round 1
// baseline (2523.934 us; speedup 1.0000x reference)
//
#include <hip/hip_runtime.h>
#include <hip/hip_bf16.h>
#include <stdint.h>

// PointNet++ Set Abstraction: FPS -> ball query -> gather -> 3x(conv1x1+BN+ReLU) -> maxpool
// B=8 N=8192 C=64, npoint=1024, r=0.2, nsample=32, MLP 67->64->64->128, BN_EPS=1e-3
//
// Exactness notes:
//  * FPS / ball query distances use __fmul_rn/__fadd_rn (NO fma contraction) in the
//    order ((dx*dx + dy*dy) + dz*dz) to match XLA-CPU's mul + left-assoc reduce.
//  * FPS argmax tie-break = first (lowest) index, via u64 key (distbits<<32)|~idx.
//  * Ball query keeps the first 32 valid indices in ASCENDING index order (matches
//    the sort-of-sentinel reference), pads with the first valid index.
//  * max-over-k commutes with relu(bn(.)) since bn slope = gamma*rsqrt(v+eps) > 0
//    (gamma==1 here) -> store only per-(b,s) channel max of z2.

#define ROWS 262144            // B*S*K = 8*1024*32
#define INV_CNT (1.0f/262144.0f)

__device__ __forceinline__ float bf2f(unsigned int v) {
    return __uint_as_float(v << 16);
}
__device__ __forceinline__ unsigned int f2bf(float f) {
    unsigned int u = __float_as_uint(f);
    return (u + 0x7fffu + ((u >> 16) & 1u)) >> 16;   // RNE
}

// ---------------- FPS: one block per batch, 1024 threads, 8 pts/thread ----------------
__global__ __launch_bounds__(1024) void fps_kernel(const float* __restrict__ xyz,
                                                   float* __restrict__ nxyz,
                                                   float* __restrict__ out_nxyz) {
    const int b = blockIdx.x;
    const int t = threadIdx.x;
    const float* xb = xyz + (size_t)b * 8192 * 3;
    float px[8], py[8], pz[8], dist[8];
#pragma unroll
    for (int i = 0; i < 8; ++i) {
        int p = t + i * 1024;
        px[i] = xb[p*3+0]; py[i] = xb[p*3+1]; pz[i] = xb[p*3+2];
        dist[i] = 1e10f;
    }
    __shared__ float sc[3];
    __shared__ unsigned long long swk[16];
    int far = 0;
    for (int it = 0; it < 1024; ++it) {
        if (t == (far & 1023)) {           // owner broadcasts centroid coords
            int i = far >> 10;
            sc[0] = px[i]; sc[1] = py[i]; sc[2] = pz[i];
        }
        __syncthreads();                   // A: centroid visible
        float cx = sc[0], cy = sc[1], cz = sc[2];
        if (t == 0) {                      // record index BEFORE update (scan semantics)
            size_t o = (size_t)(b*1024 + it) * 3;
            nxyz[o] = cx; nxyz[o+1] = cy; nxyz[o+2] = cz;
            out_nxyz[o] = cx; out_nxyz[o+1] = cy; out_nxyz[o+2] = cz;
        }
        unsigned long long bk = 0ull;
#pragma unroll
        for (int i = 0; i < 8; ++i) {
            float dx = __fsub_rn(px[i], cx);
            float dy = __fsub_rn(py[i], cy);
            float dz = __fsub_rn(pz[i], cz);
            float d = __fadd_rn(__fadd_rn(__fmul_rn(dx,dx), __fmul_rn(dy,dy)), __fmul_rn(dz,dz));
            float nd = fminf(dist[i], d);
            dist[i] = nd;
            unsigned long long key = ((unsigned long long)__float_as_uint(nd) << 32)
                                   | (unsigned int)~(unsigned int)(t + i*1024);
            bk = (key > bk) ? key : bk;
        }
        // wave64 max-reduce of u64 key via paired 32-bit shuffles
        unsigned int lo = (unsigned int)bk, hi = (unsigned int)(bk >> 32);
#pragma unroll
        for (int off = 32; off >= 1; off >>= 1) {
            unsigned int olo = __shfl_down(lo, off);
            unsigned int ohi = __shfl_down(hi, off);
            unsigned long long ok = ((unsigned long long)ohi << 32) | olo;
            unsigned long long ck = ((unsigned long long)hi  << 32) | lo;
            if (ok > ck) { lo = olo; hi = ohi; }
        }
        if ((t & 63) == 0) swk[t >> 6] = ((unsigned long long)hi << 32) | lo;
        __syncthreads();                   // B: wave partials visible
        unsigned long long fk = swk[0];
#pragma unroll
        for (int w = 1; w < 16; ++w) {
            unsigned long long ok = swk[w];
            fk = (ok > fk) ? ok : fk;
        }
        far = (int)(~(unsigned int)fk);
    }
}

// ---------------- Ball query: one wave per center ----------------
__global__ __launch_bounds__(256) void ballquery_kernel(const float* __restrict__ xyz,
                                                        const float* __restrict__ nxyz,
                                                        int* __restrict__ idxbuf) {
    const int wib = threadIdx.x >> 6;
    const int lane = threadIdx.x & 63;
    const int c = blockIdx.x * 4 + wib;        // center id in [0, 8192)
    const int b = c >> 10;
    const float* xb = xyz + (size_t)b * 8192 * 3;
    const float cx = nxyz[c*3+0], cy = nxyz[c*3+1], cz = nxyz[c*3+2];
    const float R2 = 0.04f;                    // f32(0.2*0.2): valid iff !(sqr > R2)
    int count = 0, first = 0;
    int* ob = idxbuf + (size_t)c * 32;
    for (int base = 0; base < 8192; base += 64) {
        int i = base + lane;
        float dx = __fsub_rn(xb[i*3+0], cx);
        float dy = __fsub_rn(xb[i*3+1], cy);
        float dz = __fsub_rn(xb[i*3+2], cz);
        float sq = __fadd_rn(__fadd_rn(__fmul_rn(dx,dx), __fmul_rn(dy,dy)), __fmul_rn(dz,dz));
        bool pass = !(sq > R2);
        unsigned long long mask = __ballot(pass);
        if (count == 0 && mask) first = base + (int)__builtin_ctzll(mask);
        int pos = count + (int)__popcll(mask & ((1ull << lane) - 1ull));
        if (pass && pos < 32) ob[pos] = i;
        count += (int)__popcll(mask);
        if (count >= 32) break;
    }
    if (count < 32 && lane >= count && lane < 32) ob[lane] = first;
}

// ---------------- Layer 0: gather(67) @ w0(67x64) -> z0 bf16 + stats ----------------
__global__ __launch_bounds__(256) void layer0_kernel(
        const float* __restrict__ xyz, const float* __restrict__ points,
        const float* __restrict__ nxyz, const int* __restrict__ idxbuf,
        const float* __restrict__ w0, unsigned short* __restrict__ z0,
        float* __restrict__ stats0) {
    __shared__ float ws[67][64];
    __shared__ float xs[64][68];
    __shared__ float ssum[64], ssq[64];
    const int tid = threadIdx.x;
    for (int i = tid; i < 67*64; i += 256) ws[i>>6][i&63] = w0[i];
    if (tid < 64) { ssum[tid] = 0.f; ssq[tid] = 0.f; }
    const int rl = tid >> 2, tl = tid & 3;
    const int row = blockIdx.x * 64 + rl;
    const int b = row >> 15;
    const int s = (row >> 5) & 1023;
    const int gi = idxbuf[row];
    const float* pb = points + ((size_t)(b*8192 + gi)) * 64;
    for (int e = tl; e < 67; e += 4) {
        float v;
        if (e < 3) v = xyz[(size_t)(b*8192+gi)*3 + e] - nxyz[(size_t)(b*1024+s)*3 + e];
        else       v = pb[e-3];
        xs[rl][e] = v;
    }
    __syncthreads();
    float acc[16];
#pragma unroll
    for (int j = 0; j < 16; ++j) acc[j] = 0.f;
    for (int k = 0; k < 67; ++k) {
        float xv = xs[rl][k];
        const float* wr = &ws[k][tl*16];
#pragma unroll
        for (int j = 0; j < 16; ++j) acc[j] = fmaf(xv, wr[j], acc[j]);
    }
    uint4 u0, u1;
    u0.x = f2bf(acc[0])  | (f2bf(acc[1])  << 16);
    u0.y = f2bf(acc[2])  | (f2bf(acc[3])  << 16);
    u0.z = f2bf(acc[4])  | (f2bf(acc[5])  << 16);
    u0.w = f2bf(acc[6])  | (f2bf(acc[7])  << 16);
    u1.x = f2bf(acc[8])  | (f2bf(acc[9])  << 16);
    u1.y = f2bf(acc[10]) | (f2bf(acc[11]) << 16);
    u1.z = f2bf(acc[12]) | (f2bf(acc[13]) << 16);
    u1.w = f2bf(acc[14]) | (f2bf(acc[15]) << 16);
    uint4* zp = (uint4*)(z0 + (size_t)row * 64) + tl*2;
    zp[0] = u0; zp[1] = u1;
#pragma unroll
    for (int j = 0; j < 16; ++j) {
        atomicAdd(&ssum[tl*16+j], acc[j]);
        atomicAdd(&ssq[tl*16+j], acc[j]*acc[j]);
    }
    __syncthreads();
    if (tid < 64) {
        atomicAdd(&stats0[tid], ssum[tid]);
        atomicAdd(&stats0[64+tid], ssq[tid]);
    }
}

// ---------------- Layer 1: relu(bn0(z0)) @ w1(64x64) -> z1 bf16 + stats ----------------
__global__ __launch_bounds__(256) void layer1_kernel(
        const unsigned short* __restrict__ z0, const float* __restrict__ stats0,
        const float* __restrict__ gamma0, const float* __restrict__ beta0,
        const float* __restrict__ w1, unsigned short* __restrict__ z1,
        float* __restrict__ stats1) {
    __shared__ float ws[64][64];
    __shared__ float xs[64][68];
    __shared__ float scale[64], shift[64];
    __shared__ float ssum[64], ssq[64];
    const int tid = threadIdx.x;
    for (int i = tid; i < 64*64; i += 256) ws[i>>6][i&63] = w1[i];
    if (tid < 64) {
        float m = stats0[tid] * INV_CNT;
        float v = stats0[64+tid] * INV_CNT - m*m;
        float rs = rsqrtf(v + 1e-3f);
        float sc = gamma0[tid] * rs;
        scale[tid] = sc; shift[tid] = beta0[tid] - m*sc;
        ssum[tid] = 0.f; ssq[tid] = 0.f;
    }
    const int rl = tid >> 2, tl = tid & 3;
    const size_t row = (size_t)blockIdx.x * 64 + rl;
    const uint4* zr = (const uint4*)(z0 + row * 64) + tl*2;
    uint4 a = zr[0], bq = zr[1];
    float* xr = &xs[rl][tl*16];
    xr[0] = bf2f(a.x & 0xffffu);  xr[1] = bf2f(a.x >> 16);
    xr[2] = bf2f(a.y & 0xffffu);  xr[3] = bf2f(a.y >> 16);
    xr[4] = bf2f(a.z & 0xffffu);  xr[5] = bf2f(a.z >> 16);
    xr[6] = bf2f(a.w & 0xffffu);  xr[7] = bf2f(a.w >> 16);
    xr[8] = bf2f(bq.x & 0xffffu); xr[9] = bf2f(bq.x >> 16);
    xr[10] = bf2f(bq.y & 0xffffu); xr[11] = bf2f(bq.y >> 16);
    xr[12] = bf2f(bq.z & 0xffffu); xr[13] = bf2f(bq.z >> 16);
    xr[14] = bf2f(bq.w & 0xffffu); xr[15] = bf2f(bq.w >> 16);
    __syncthreads();     // scale ready + raw xs ready
#pragma unroll
    for (int j = 0; j < 16; ++j) {
        int e = tl*16 + j;
        xs[rl][e] = fmaxf(xs[rl][e]*scale[e] + shift[e], 0.f);
    }
    __syncthreads();
    float acc[16];
#pragma unroll
    for (int j = 0; j < 16; ++j) acc[j] = 0.f;
    for (int k = 0; k < 64; ++k) {
        float xv = xs[rl][k];
        const float* wr = &ws[k][tl*16];
#pragma unroll
        for (int j = 0; j < 16; ++j) acc[j] = fmaf(xv, wr[j], acc[j]);
    }
    uint4 u0, u1;
    u0.x = f2bf(acc[0])  | (f2bf(acc[1])  << 16);
    u0.y = f2bf(acc[2])  | (f2bf(acc[3])  << 16);
    u0.z = f2bf(acc[4])  | (f2bf(acc[5])  << 16);
    u0.w = f2bf(acc[6])  | (f2bf(acc[7])  << 16);
    u1.x = f2bf(acc[8])  | (f2bf(acc[9])  << 16);
    u1.y = f2bf(acc[10]) | (f2bf(acc[11]) << 16);
    u1.z = f2bf(acc[12]) | (f2bf(acc[13]) << 16);
    u1.w = f2bf(acc[14]) | (f2bf(acc[15]) << 16);
    uint4* zp = (uint4*)(z1 + row * 64) + tl*2;
    zp[0] = u0; zp[1] = u1;
#pragma unroll
    for (int j = 0; j < 16; ++j) {
        atomicAdd(&ssum[tl*16+j], acc[j]);
        atomicAdd(&ssq[tl*16+j], acc[j]*acc[j]);
    }
    __syncthreads();
    if (tid < 64) {
        atomicAdd(&stats1[tid], ssum[tid]);
        atomicAdd(&stats1[64+tid], ssq[tid]);
    }
}

// ------- Layer 2: relu(bn1(z1)) @ w2(64x128); store per-(b,s) channel max + stats -------
__global__ __launch_bounds__(256) void layer2_kernel(
        const unsigned short* __restrict__ z1, const float* __restrict__ stats1,
        const float* __restrict__ gamma1, const float* __restrict__ beta1,
        const float* __restrict__ w2, float* __restrict__ maxz2,
        float* __restrict__ stats2) {
    __shared__ float ws[64][128];
    __shared__ float xs[32][68];
    __shared__ float scale[64], shift[64];
    __shared__ float ssum[128], ssq[128];
    __shared__ float mx[4][128];
    const int tid = threadIdx.x;
    for (int i = tid; i < 64*128; i += 256) ws[i>>7][i&127] = w2[i];
    if (tid < 64) {
        float m = stats1[tid] * INV_CNT;
        float v = stats1[64+tid] * INV_CNT - m*m;
        float rs = rsqrtf(v + 1e-3f);
        float sc = gamma1[tid] * rs;
        scale[tid] = sc; shift[tid] = beta1[tid] - m*sc;
    }
    if (tid < 128) { ssum[tid] = 0.f; ssq[tid] = 0.f; }
    const int kr = tid >> 3, cg = tid & 7;     // kr: sample k in [0,32), cg: 16-channel group
    const size_t row = (size_t)blockIdx.x * 32 + kr;
    const uint4* zr = (const uint4*)(z1 + row * 64) + cg;
    uint4 a = zr[0];
    float* xr = &xs[kr][cg*8];
    xr[0] = bf2f(a.x & 0xffffu); xr[1] = bf2f(a.x >> 16);
    xr[2] = bf2f(a.y & 0xffffu); xr[3] = bf2f(a.y >> 16);
    xr[4] = bf2f(a.z & 0xffffu); xr[5] = bf2f(a.z >> 16);
    xr[6] = bf2f(a.w & 0xffffu); xr[7] = bf2f(a.w >> 16);
    __syncthreads();
#pragma unroll
    for (int j = 0; j < 8; ++j) {
        int e = cg*8 + j;
        xs[kr][e] = fmaxf(xs[kr][e]*scale[e] + shift[e], 0.f);
    }
    __syncthreads();
    float acc[16];
#pragma unroll
    for (int j = 0; j < 16; ++j) acc[j] = 0.f;
    for (int k = 0; k < 64; ++k) {
        float xv = xs[kr][k];
        const float* wr = &ws[k][cg*16];
#pragma unroll
        for (int j = 0; j < 16; ++j) acc[j] = fmaf(xv, wr[j], acc[j]);
    }
#pragma unroll
    for (int j = 0; j < 16; ++j) {
        atomicAdd(&ssum[cg*16+j], acc[j]);
        atomicAdd(&ssq[cg*16+j], acc[j]*acc[j]);
    }
    // max over k: shuffle (lanes with same cg are stride-8), then cross-wave via LDS
#pragma unroll
    for (int off = 32; off >= 8; off >>= 1) {
#pragma unroll
        for (int j = 0; j < 16; ++j) {
            float ov = __shfl_down(acc[j], off);
            acc[j] = fmaxf(acc[j], ov);
        }
    }
    const int wv = tid >> 6, ln = tid & 63;
    if (ln < 8) {
#pragma unroll
        for (int j = 0; j < 16; ++j) mx[wv][ln*16+j] = acc[j];
    }
    __syncthreads();
    if (tid < 128) {
        float m = fmaxf(fmaxf(mx[0][tid], mx[1][tid]), fmaxf(mx[2][tid], mx[3][tid]));
        maxz2[(size_t)blockIdx.x * 128 + tid] = m;
        atomicAdd(&stats2[tid], ssum[tid]);
        atomicAdd(&stats2[128+tid], ssq[tid]);
    }
}

// ---------------- Final: out = relu(bn2(maxz2)) ----------------
__global__ __launch_bounds__(256) void final_kernel(
        const float* __restrict__ maxz2, const float* __restrict__ stats2,
        const float* __restrict__ gamma2, const float* __restrict__ beta2,
        float* __restrict__ out) {
    const int i = blockIdx.x * 256 + threadIdx.x;    // over 8*1024*128
    const int f = i & 127;
    float m = stats2[f] * INV_CNT;
    float v = stats2[128+f] * INV_CNT - m*m;
    float rs = rsqrtf(v + 1e-3f);
    out[24576 + i] = fmaxf(gamma2[f]*((maxz2[i]-m)*rs) + beta2[f], 0.f);
}

extern "C" void kernel_launch(void* const* d_in, const int* in_sizes, int n_in,
                              void* d_out, int out_size, void* d_ws, size_t ws_size,
                              hipStream_t stream) {
    const float* xyz    = (const float*)d_in[0];
    const float* points = (const float*)d_in[1];
    const float* w0     = (const float*)d_in[2];
    const float* g0     = (const float*)d_in[3];
    const float* b0     = (const float*)d_in[4];
    const float* w1     = (const float*)d_in[5];
    const float* g1     = (const float*)d_in[6];
    const float* b1     = (const float*)d_in[7];
    const float* w2     = (const float*)d_in[8];
    const float* g2     = (const float*)d_in[9];
    const float* b2     = (const float*)d_in[10];
    float* out = (float*)d_out;
    char* ws = (char*)d_ws;

    // workspace layout (bytes), all 256-aligned:
    float* nxyz            = (float*)(ws + 0);          // 24576 f32   = 98304 B
    int*   idxbuf          = (int*)  (ws + 98304);      // 262144 i32  = 1048576 B
    float* stats           = (float*)(ws + 1146880);    // 512 f32 (s0:128, s1:128, s2:256)
    unsigned short* z0     = (unsigned short*)(ws + 1148928);   // 32 MB bf16
    unsigned short* z1     = (unsigned short*)(ws + 34703360);  // 32 MB bf16
    float* maxz2           = (float*)(ws + 68257792);   // 4 MB f32
    // total ~72.5 MB

    hipMemsetAsync(stats, 0, 512 * sizeof(float), stream);
    fps_kernel<<<8, 1024, 0, stream>>>(xyz, nxyz, out);
    ballquery_kernel<<<2048, 256, 0, stream>>>(xyz, nxyz, idxbuf);
    layer0_kernel<<<4096, 256, 0, stream>>>(xyz, points, nxyz, idxbuf, w0, z0, stats);
    layer1_kernel<<<4096, 256, 0, stream>>>(z0, stats, g0, b0, w1, z1, stats + 128);
    layer2_kernel<<<8192, 256, 0, stream>>>(z1, stats + 128, g1, b1, w2, maxz2, stats + 256);
    final_kernel<<<4096, 256, 0, stream>>>(maxz2, stats + 256, g2, b2, out);
}

// Round 2
// 2254.098 us; speedup vs baseline: 1.1197x; 1.1197x over previous
//
#include <hip/hip_runtime.h>
#include <hip/hip_bf16.h>
#include <stdint.h>

// PointNet++ Set Abstraction: FPS -> ball query -> gather -> 3x(conv1x1+BN+ReLU) -> maxpool
// B=8 N=8192 C=64, npoint=1024, r=0.2, nsample=32, MLP 67->64->64->128, BN_EPS=1e-3
//
// Exactness notes:
//  * FPS / ball query distances use __fmul_rn/__fadd_rn (NO fma contraction) in the
//    order ((dx*dx + dy*dy) + dz*dz) to match XLA-CPU's mul + left-assoc reduce.
//  * FPS argmax tie-break = first (lowest) index: within-thread via strict > over
//    ascending indices; across threads via u64 key (distbits<<32)|~idx maximized.
//  * Ball query keeps the first 32 valid indices in ASCENDING index order, pads with
//    the first valid index.
//  * max-over-k commutes with relu(bn(.)) since bn slope > 0 -> store only
//    per-(b,s) channel max of z2.

#define ROWS 262144            // B*S*K = 8*1024*32
#define INV_CNT (1.0f/262144.0f)

__device__ __forceinline__ float bf2f(unsigned int v) {
    return __uint_as_float(v << 16);
}
__device__ __forceinline__ unsigned int f2bf(float f) {
    unsigned int u = __float_as_uint(f);
    return (u + 0x7fffu + ((u >> 16) & 1u)) >> 16;   // RNE
}

// ---------------- FPS: one block per batch, 1024 threads, 8 pts/thread ----------------
// Coords mirrored in LDS so every thread can read the centroid directly (no owner
// broadcast). ONE barrier per iteration; swk double-buffered to avoid WAR.
__global__ __launch_bounds__(1024) void fps_kernel(const float* __restrict__ xyz,
                                                   float* __restrict__ nxyz,
                                                   float* __restrict__ out_nxyz) {
    const int b = blockIdx.x;
    const int t = threadIdx.x;
    const int lane = t & 63;
    const int wv = t >> 6;
    const float* xb = xyz + (size_t)b * 8192 * 3;
    __shared__ float sx[8192], sy[8192], sz[8192];          // 96 KB coord mirror
    __shared__ unsigned long long swk[2][16];
    float px[8], py[8], pz[8], dist[8];
#pragma unroll
    for (int i = 0; i < 8; ++i) {
        int p = t + i * 1024;
        float x = xb[p*3+0], y = xb[p*3+1], z = xb[p*3+2];
        px[i] = x; py[i] = y; pz[i] = z;
        sx[p] = x; sy[p] = y; sz[p] = z;
        dist[i] = 1e10f;
    }
    __syncthreads();
    int far = 0;
    for (int it = 0; it < 1024; ++it) {
        float cx = sx[far], cy = sy[far], cz = sz[far];     // uniform-addr LDS broadcast
        if (t == 0) {                                       // record BEFORE update
            size_t o = (size_t)(b*1024 + it) * 3;
            nxyz[o] = cx; nxyz[o+1] = cy; nxyz[o+2] = cz;
            out_nxyz[o] = cx; out_nxyz[o+1] = cy; out_nxyz[o+2] = cz;
        }
        float bestd = -1.0f;
        int bi = 0;                                         // local slot in [0,8)
#pragma unroll
        for (int i = 0; i < 8; ++i) {
            float dx = __fsub_rn(px[i], cx);
            float dy = __fsub_rn(py[i], cy);
            float dz = __fsub_rn(pz[i], cz);
            float d = __fadd_rn(__fadd_rn(__fmul_rn(dx,dx), __fmul_rn(dy,dy)), __fmul_rn(dz,dz));
            float nd = fminf(dist[i], d);
            dist[i] = nd;
            bool gt = nd > bestd;                           // strict >: first-index tie-break
            bi = gt ? i : bi;
            bestd = gt ? nd : bestd;
        }
        unsigned int lo = ~(unsigned int)(t + bi * 1024);
        unsigned int hi = __float_as_uint(bestd);
        // wave64 max-reduce of (hi,lo) u64 key
#pragma unroll
        for (int off = 32; off >= 1; off >>= 1) {
            unsigned int olo = __shfl_down(lo, off);
            unsigned int ohi = __shfl_down(hi, off);
            unsigned long long ok = ((unsigned long long)ohi << 32) | olo;
            unsigned long long ck = ((unsigned long long)hi  << 32) | lo;
            if (ok > ck) { lo = olo; hi = ohi; }
        }
        if (lane == 0) swk[it & 1][wv] = ((unsigned long long)hi << 32) | lo;
        __syncthreads();                                    // the only barrier per iter
        unsigned long long k = swk[it & 1][lane & 15];      // 16 partials, bcast-read
        unsigned int flo = (unsigned int)k, fhi = (unsigned int)(k >> 32);
#pragma unroll
        for (int off = 8; off >= 1; off >>= 1) {            // xor-butterfly over 16
            unsigned int olo = __shfl_xor(flo, off);
            unsigned int ohi = __shfl_xor(fhi, off);
            unsigned long long ok = ((unsigned long long)ohi << 32) | olo;
            unsigned long long ck = ((unsigned long long)fhi << 32) | flo;
            if (ok > ck) { flo = olo; fhi = ohi; }
        }
        far = (int)(~flo) & 8191;
    }
}

// ---------------- Ball query: one wave per center ----------------
__global__ __launch_bounds__(256) void ballquery_kernel(const float* __restrict__ xyz,
                                                        const float* __restrict__ nxyz,
                                                        int* __restrict__ idxbuf) {
    const int wib = threadIdx.x >> 6;
    const int lane = threadIdx.x & 63;
    const int c = blockIdx.x * 4 + wib;        // center id in [0, 8192)
    const int b = c >> 10;
    const float* xb = xyz + (size_t)b * 8192 * 3;
    const float cx = nxyz[c*3+0], cy = nxyz[c*3+1], cz = nxyz[c*3+2];
    const float R2 = 0.04f;                    // valid iff !(sqr > R2)
    int count = 0, first = 0;
    int* ob = idxbuf + (size_t)c * 32;
    for (int base = 0; base < 8192; base += 64) {
        int i = base + lane;
        float dx = __fsub_rn(xb[i*3+0], cx);
        float dy = __fsub_rn(xb[i*3+1], cy);
        float dz = __fsub_rn(xb[i*3+2], cz);
        float sq = __fadd_rn(__fadd_rn(__fmul_rn(dx,dx), __fmul_rn(dy,dy)), __fmul_rn(dz,dz));
        bool pass = !(sq > R2);
        unsigned long long mask = __ballot(pass);
        if (count == 0 && mask) first = base + (int)__builtin_ctzll(mask);
        int pos = count + (int)__popcll(mask & ((1ull << lane) - 1ull));
        if (pass && pos < 32) ob[pos] = i;
        count += (int)__popcll(mask);
        if (count >= 32) break;
    }
    if (count < 32 && lane >= count && lane < 32) ob[lane] = first;
}

// ---------------- Layer 0: gather(67) @ w0(67x64) -> z0 bf16 + stats ----------------
__global__ __launch_bounds__(256) void layer0_kernel(
        const float* __restrict__ xyz, const float* __restrict__ points,
        const float* __restrict__ nxyz, const int* __restrict__ idxbuf,
        const float* __restrict__ w0, unsigned short* __restrict__ z0,
        float* __restrict__ stats0) {
    __shared__ float ws[67][64];
    __shared__ float xs[64][68];
    __shared__ float ssum[64], ssq[64];
    const int tid = threadIdx.x;
    for (int i = tid; i < 67*64; i += 256) ws[i>>6][i&63] = w0[i];
    if (tid < 64) { ssum[tid] = 0.f; ssq[tid] = 0.f; }
    const int rl = tid >> 2, tl = tid & 3;
    const int row = blockIdx.x * 64 + rl;
    const int b = row >> 15;
    const int s = (row >> 5) & 1023;
    const int gi = idxbuf[row];
    const float* pb = points + ((size_t)(b*8192 + gi)) * 64;
    for (int e = tl; e < 67; e += 4) {
        float v;
        if (e < 3) v = xyz[(size_t)(b*8192+gi)*3 + e] - nxyz[(size_t)(b*1024+s)*3 + e];
        else       v = pb[e-3];
        xs[rl][e] = v;
    }
    __syncthreads();
    float acc[16];
#pragma unroll
    for (int j = 0; j < 16; ++j) acc[j] = 0.f;
    for (int k = 0; k < 67; ++k) {
        float xv = xs[rl][k];
        const float* wr = &ws[k][tl*16];
#pragma unroll
        for (int j = 0; j < 16; ++j) acc[j] = fmaf(xv, wr[j], acc[j]);
    }
    uint4 u0, u1;
    u0.x = f2bf(acc[0])  | (f2bf(acc[1])  << 16);
    u0.y = f2bf(acc[2])  | (f2bf(acc[3])  << 16);
    u0.z = f2bf(acc[4])  | (f2bf(acc[5])  << 16);
    u0.w = f2bf(acc[6])  | (f2bf(acc[7])  << 16);
    u1.x = f2bf(acc[8])  | (f2bf(acc[9])  << 16);
    u1.y = f2bf(acc[10]) | (f2bf(acc[11]) << 16);
    u1.z = f2bf(acc[12]) | (f2bf(acc[13]) << 16);
    u1.w = f2bf(acc[14]) | (f2bf(acc[15]) << 16);
    uint4* zp = (uint4*)(z0 + (size_t)row * 64) + tl*2;
    zp[0] = u0; zp[1] = u1;
#pragma unroll
    for (int j = 0; j < 16; ++j) {
        atomicAdd(&ssum[tl*16+j], acc[j]);
        atomicAdd(&ssq[tl*16+j], acc[j]*acc[j]);
    }
    __syncthreads();
    if (tid < 64) {
        atomicAdd(&stats0[tid], ssum[tid]);
        atomicAdd(&stats0[64+tid], ssq[tid]);
    }
}

// ---------------- Layer 1: relu(bn0(z0)) @ w1(64x64) -> z1 bf16 + stats ----------------
__global__ __launch_bounds__(256) void layer1_kernel(
        const unsigned short* __restrict__ z0, const float* __restrict__ stats0,
        const float* __restrict__ gamma0, const float* __restrict__ beta0,
        const float* __restrict__ w1, unsigned short* __restrict__ z1,
        float* __restrict__ stats1) {
    __shared__ float ws[64][64];
    __shared__ float xs[64][68];
    __shared__ float scale[64], shift[64];
    __shared__ float ssum[64], ssq[64];
    const int tid = threadIdx.x;
    for (int i = tid; i < 64*64; i += 256) ws[i>>6][i&63] = w1[i];
    if (tid < 64) {
        float m = stats0[tid] * INV_CNT;
        float v = stats0[64+tid] * INV_CNT - m*m;
        float rs = rsqrtf(v + 1e-3f);
        float sc = gamma0[tid] * rs;
        scale[tid] = sc; shift[tid] = beta0[tid] - m*sc;
        ssum[tid] = 0.f; ssq[tid] = 0.f;
    }
    const int rl = tid >> 2, tl = tid & 3;
    const size_t row = (size_t)blockIdx.x * 64 + rl;
    const uint4* zr = (const uint4*)(z0 + row * 64) + tl*2;
    uint4 a = zr[0], bq = zr[1];
    float* xr = &xs[rl][tl*16];
    xr[0] = bf2f(a.x & 0xffffu);  xr[1] = bf2f(a.x >> 16);
    xr[2] = bf2f(a.y & 0xffffu);  xr[3] = bf2f(a.y >> 16);
    xr[4] = bf2f(a.z & 0xffffu);  xr[5] = bf2f(a.z >> 16);
    xr[6] = bf2f(a.w & 0xffffu);  xr[7] = bf2f(a.w >> 16);
    xr[8] = bf2f(bq.x & 0xffffu); xr[9] = bf2f(bq.x >> 16);
    xr[10] = bf2f(bq.y & 0xffffu); xr[11] = bf2f(bq.y >> 16);
    xr[12] = bf2f(bq.z & 0xffffu); xr[13] = bf2f(bq.z >> 16);
    xr[14] = bf2f(bq.w & 0xffffu); xr[15] = bf2f(bq.w >> 16);
    __syncthreads();     // scale ready + raw xs ready
#pragma unroll
    for (int j = 0; j < 16; ++j) {
        int e = tl*16 + j;
        xs[rl][e] = fmaxf(xs[rl][e]*scale[e] + shift[e], 0.f);
    }
    __syncthreads();
    float acc[16];
#pragma unroll
    for (int j = 0; j < 16; ++j) acc[j] = 0.f;
    for (int k = 0; k < 64; ++k) {
        float xv = xs[rl][k];
        const float* wr = &ws[k][tl*16];
#pragma unroll
        for (int j = 0; j < 16; ++j) acc[j] = fmaf(xv, wr[j], acc[j]);
    }
    uint4 u0, u1;
    u0.x = f2bf(acc[0])  | (f2bf(acc[1])  << 16);
    u0.y = f2bf(acc[2])  | (f2bf(acc[3])  << 16);
    u0.z = f2bf(acc[4])  | (f2bf(acc[5])  << 16);
    u0.w = f2bf(acc[6])  | (f2bf(acc[7])  << 16);
    u1.x = f2bf(acc[8])  | (f2bf(acc[9])  << 16);
    u1.y = f2bf(acc[10]) | (f2bf(acc[11]) << 16);
    u1.z = f2bf(acc[12]) | (f2bf(acc[13]) << 16);
    u1.w = f2bf(acc[14]) | (f2bf(acc[15]) << 16);
    uint4* zp = (uint4*)(z1 + row * 64) + tl*2;
    zp[0] = u0; zp[1] = u1;
#pragma unroll
    for (int j = 0; j < 16; ++j) {
        atomicAdd(&ssum[tl*16+j], acc[j]);
        atomicAdd(&ssq[tl*16+j], acc[j]*acc[j]);
    }
    __syncthreads();
    if (tid < 64) {
        atomicAdd(&stats1[tid], ssum[tid]);
        atomicAdd(&stats1[64+tid], ssq[tid]);
    }
}

// ------- Layer 2: relu(bn1(z1)) @ w2(64x128); store per-(b,s) channel max + stats -------
__global__ __launch_bounds__(256) void layer2_kernel(
        const unsigned short* __restrict__ z1, const float* __restrict__ stats1,
        const float* __restrict__ gamma1, const float* __restrict__ beta1,
        const float* __restrict__ w2, float* __restrict__ maxz2,
        float* __restrict__ stats2) {
    __shared__ float ws[64][128];
    __shared__ float xs[32][68];
    __shared__ float scale[64], shift[64];
    __shared__ float ssum[128], ssq[128];
    __shared__ float mx[4][128];
    const int tid = threadIdx.x;
    for (int i = tid; i < 64*128; i += 256) ws[i>>7][i&127] = w2[i];
    if (tid < 64) {
        float m = stats1[tid] * INV_CNT;
        float v = stats1[64+tid] * INV_CNT - m*m;
        float rs = rsqrtf(v + 1e-3f);
        float sc = gamma1[tid] * rs;
        scale[tid] = sc; shift[tid] = beta1[tid] - m*sc;
    }
    if (tid < 128) { ssum[tid] = 0.f; ssq[tid] = 0.f; }
    const int kr = tid >> 3, cg = tid & 7;     // kr: sample k in [0,32), cg: 16-channel group
    const size_t row = (size_t)blockIdx.x * 32 + kr;
    const uint4* zr = (const uint4*)(z1 + row * 64) + cg;
    uint4 a = zr[0];
    float* xr = &xs[kr][cg*8];
    xr[0] = bf2f(a.x & 0xffffu); xr[1] = bf2f(a.x >> 16);
    xr[2] = bf2f(a.y & 0xffffu); xr[3] = bf2f(a.y >> 16);
    xr[4] = bf2f(a.z & 0xffffu); xr[5] = bf2f(a.z >> 16);
    xr[6] = bf2f(a.w & 0xffffu); xr[7] = bf2f(a.w >> 16);
    __syncthreads();
#pragma unroll
    for (int j = 0; j < 8; ++j) {
        int e = cg*8 + j;
        xs[kr][e] = fmaxf(xs[kr][e]*scale[e] + shift[e], 0.f);
    }
    __syncthreads();
    float acc[16];
#pragma unroll
    for (int j = 0; j < 16; ++j) acc[j] = 0.f;
    for (int k = 0; k < 64; ++k) {
        float xv = xs[kr][k];
        const float* wr = &ws[k][cg*16];
#pragma unroll
        for (int j = 0; j < 16; ++j) acc[j] = fmaf(xv, wr[j], acc[j]);
    }
#pragma unroll
    for (int j = 0; j < 16; ++j) {
        atomicAdd(&ssum[cg*16+j], acc[j]);
        atomicAdd(&ssq[cg*16+j], acc[j]*acc[j]);
    }
    // max over k: shuffle (lanes with same cg are stride-8), then cross-wave via LDS
#pragma unroll
    for (int off = 32; off >= 8; off >>= 1) {
#pragma unroll
        for (int j = 0; j < 16; ++j) {
            float ov = __shfl_down(acc[j], off);
            acc[j] = fmaxf(acc[j], ov);
        }
    }
    const int wv = tid >> 6, ln = tid & 63;
    if (ln < 8) {
#pragma unroll
        for (int j = 0; j < 16; ++j) mx[wv][ln*16+j] = acc[j];
    }
    __syncthreads();
    if (tid < 128) {
        float m = fmaxf(fmaxf(mx[0][tid], mx[1][tid]), fmaxf(mx[2][tid], mx[3][tid]));
        maxz2[(size_t)blockIdx.x * 128 + tid] = m;
        atomicAdd(&stats2[tid], ssum[tid]);
        atomicAdd(&stats2[128+tid], ssq[tid]);
    }
}

// ---------------- Final: out = relu(bn2(maxz2)) ----------------
__global__ __launch_bounds__(256) void final_kernel(
        const float* __restrict__ maxz2, const float* __restrict__ stats2,
        const float* __restrict__ gamma2, const float* __restrict__ beta2,
        float* __restrict__ out) {
    const int i = blockIdx.x * 256 + threadIdx.x;    // over 8*1024*128
    const int f = i & 127;
    float m = stats2[f] * INV_CNT;
    float v = stats2[128+f] * INV_CNT - m*m;
    float rs = rsqrtf(v + 1e-3f);
    out[24576 + i] = fmaxf(gamma2[f]*((maxz2[i]-m)*rs) + beta2[f], 0.f);
}

extern "C" void kernel_launch(void* const* d_in, const int* in_sizes, int n_in,
                              void* d_out, int out_size, void* d_ws, size_t ws_size,
                              hipStream_t stream) {
    const float* xyz    = (const float*)d_in[0];
    const float* points = (const float*)d_in[1];
    const float* w0     = (const float*)d_in[2];
    const float* g0     = (const float*)d_in[3];
    const float* b0     = (const float*)d_in[4];
    const float* w1     = (const float*)d_in[5];
    const float* g1     = (const float*)d_in[6];
    const float* b1     = (const float*)d_in[7];
    const float* w2     = (const float*)d_in[8];
    const float* g2     = (const float*)d_in[9];
    const float* b2     = (const float*)d_in[10];
    float* out = (float*)d_out;
    char* ws = (char*)d_ws;

    // workspace layout (bytes), all 256-aligned:
    float* nxyz            = (float*)(ws + 0);          // 24576 f32   = 98304 B
    int*   idxbuf          = (int*)  (ws + 98304);      // 262144 i32  = 1048576 B
    float* stats           = (float*)(ws + 1146880);    // 512 f32 (s0:128, s1:128, s2:256)
    unsigned short* z0     = (unsigned short*)(ws + 1148928);   // 32 MB bf16
    unsigned short* z1     = (unsigned short*)(ws + 34703360);  // 32 MB bf16
    float* maxz2           = (float*)(ws + 68257792);   // 4 MB f32
    // total ~72.5 MB

    hipMemsetAsync(stats, 0, 512 * sizeof(float), stream);
    fps_kernel<<<8, 1024, 0, stream>>>(xyz, nxyz, out);
    ballquery_kernel<<<2048, 256, 0, stream>>>(xyz, nxyz, idxbuf);
    layer0_kernel<<<4096, 256, 0, stream>>>(xyz, points, nxyz, idxbuf, w0, z0, stats);
    layer1_kernel<<<4096, 256, 0, stream>>>(z0, stats, g0, b0, w1, z1, stats + 128);
    layer2_kernel<<<8192, 256, 0, stream>>>(z1, stats + 128, g1, b1, w2, maxz2, stats + 256);
    final_kernel<<<4096, 256, 0, stream>>>(maxz2, stats + 256, g2, b2, out);
}

// Round 3
// 1969.057 us; speedup vs baseline: 1.2818x; 1.1448x over previous
//
#include <hip/hip_runtime.h>
#include <hip/hip_bf16.h>
#include <stdint.h>

// PointNet++ Set Abstraction: FPS -> ball query -> gather -> 3x(conv1x1+BN+ReLU) -> maxpool
// B=8 N=8192 C=64, npoint=1024, r=0.2, nsample=32, MLP 67->64->64->128, BN_EPS=1e-3
//
// Exactness notes:
//  * FPS / ball query distances use __fmul_rn/__fadd_rn (NO fma contraction) in the
//    order ((dx*dx + dy*dy) + dz*dz) to match XLA-CPU's mul + left-assoc reduce.
//  * FPS argmax tie-break = first (lowest) global index:
//      - exact wave max (v_max chain preserves bits), then u32-min over candidate
//        indices of lanes equal to the max (DPP), then cross-wave u64 key
//        (distbits<<32)|~idx maximized -> highest dist, lowest idx.
//  * Ball query keeps the first 32 valid indices in ASCENDING index order, pads with
//    the first valid index.
//  * max-over-k commutes with relu(bn(.)) since bn slope > 0 -> store only
//    per-(b,s) channel max of z2.

#define ROWS 262144            // B*S*K = 8*1024*32
#define INV_CNT (1.0f/262144.0f)

__device__ __forceinline__ float bf2f(unsigned int v) {
    return __uint_as_float(v << 16);
}
__device__ __forceinline__ unsigned int f2bf(float f) {
    unsigned int u = __float_as_uint(f);
    return (u + 0x7fffu + ((u >> 16) & 1u)) >> 16;   // RNE
}

// DPP cross-lane move: lane-local, VALU-pipe (no LDS). old = self -> invalid lanes keep value.
template<int CTRL>
__device__ __forceinline__ unsigned int dpp_u32(unsigned int x) {
    return (unsigned int)__builtin_amdgcn_update_dpp((int)x, (int)x, CTRL, 0xf, 0xf, false);
}
template<int CTRL>
__device__ __forceinline__ float dpp_f32(float x) {
    return __uint_as_float(dpp_u32<CTRL>(__float_as_uint(x)));
}
// DPP ctrl encodings: ROW_SHR:n = 0x110|n, ROW_BCAST15 = 0x142, ROW_BCAST31 = 0x143

// ---------------- FPS: one block per batch, 512 threads, 16 pts/thread ----------------
__global__ __launch_bounds__(512) void fps_kernel(const float* __restrict__ xyz,
                                                  float* __restrict__ nxyz,
                                                  float* __restrict__ out_nxyz) {
    const int b = blockIdx.x;
    const int t = threadIdx.x;
    const int lane = t & 63;
    const int wv = t >> 6;                                   // 0..7
    const float* xb = xyz + (size_t)b * 8192 * 3;
    __shared__ float sx[8192], sy[8192], sz[8192];           // 96 KB coord mirror
    __shared__ unsigned int sdhi[2][8], sdlo[2][8];          // per-wave (distbits, ~idx)
    __shared__ int ch[1024];                                 // chosen index history
    float px[16], py[16], pz[16], dist[16];
#pragma unroll
    for (int i = 0; i < 16; ++i) {
        int p = t + i * 512;
        float x = xb[p*3+0], y = xb[p*3+1], z = xb[p*3+2];
        px[i] = x; py[i] = y; pz[i] = z;
        sx[p] = x; sy[p] = y; sz[p] = z;
        dist[i] = 1e10f;
    }
    __syncthreads();
    int far = 0;
    for (int it = 0; it < 1024; ++it) {
        if (t == 0) ch[it] = far;                            // record BEFORE update
        float cx = sx[far], cy = sy[far], cz = sz[far];      // uniform LDS broadcast
#pragma unroll
        for (int i = 0; i < 16; ++i) {
            float dx = __fsub_rn(px[i], cx);
            float dy = __fsub_rn(py[i], cy);
            float dz = __fsub_rn(pz[i], cz);
            float d = __fadd_rn(__fadd_rn(__fmul_rn(dx,dx), __fmul_rn(dy,dy)), __fmul_rn(dz,dz));
            dist[i] = fminf(dist[i], d);
        }
        // exact max over the 16 local dists (value-only tree)
        float td[16];
#pragma unroll
        for (int i = 0; i < 16; ++i) td[i] = dist[i];
#pragma unroll
        for (int s = 8; s >= 1; s >>= 1)
#pragma unroll
            for (int i = 0; i < s; ++i) td[i] = fmaxf(td[i], td[i+s]);
        float m = td[0];
        int bi = 0;                                          // lowest slot achieving m
#pragma unroll
        for (int i = 15; i >= 0; --i) bi = (dist[i] == m) ? i : bi;
        // wave64 max via DPP (result lands in lane 63)
        float v = m;
        v = fmaxf(v, dpp_f32<0x111>(v));
        v = fmaxf(v, dpp_f32<0x112>(v));
        v = fmaxf(v, dpp_f32<0x114>(v));
        v = fmaxf(v, dpp_f32<0x118>(v));
        v = fmaxf(v, dpp_f32<0x142>(v));
        v = fmaxf(v, dpp_f32<0x143>(v));
        float wmax = __uint_as_float((unsigned int)__builtin_amdgcn_readlane((int)__float_as_uint(v), 63));
        // lowest global index among lanes holding wmax
        unsigned int u = (m == wmax) ? (unsigned int)(t + bi * 512) : 0xffffffffu;
        { unsigned int n;
          n = dpp_u32<0x111>(u); u = (n < u) ? n : u;
          n = dpp_u32<0x112>(u); u = (n < u) ? n : u;
          n = dpp_u32<0x114>(u); u = (n < u) ? n : u;
          n = dpp_u32<0x118>(u); u = (n < u) ? n : u;
          n = dpp_u32<0x142>(u); u = (n < u) ? n : u;
          n = dpp_u32<0x143>(u); u = (n < u) ? n : u; }
        unsigned int widx = (unsigned int)__builtin_amdgcn_readlane((int)u, 63);
        if (lane == 0) {
            sdhi[it & 1][wv] = __float_as_uint(wmax);
            sdlo[it & 1][wv] = ~widx;
        }
        __syncthreads();                                     // the only barrier per iter
        unsigned int hi = sdhi[it & 1][lane & 7];
        unsigned int lo = sdlo[it & 1][lane & 7];
        // 3-step DPP u64-key max over the 8 wave partials (result in lane 7)
#define FPS_XSTEP(C) { unsigned int nh = dpp_u32<C>(hi), nl = dpp_u32<C>(lo); \
                       bool tk = (nh > hi) || (nh == hi && nl > lo);           \
                       hi = tk ? nh : hi; lo = tk ? nl : lo; }
        FPS_XSTEP(0x111)
        FPS_XSTEP(0x112)
        FPS_XSTEP(0x114)
#undef FPS_XSTEP
        far = (int)(~(unsigned int)__builtin_amdgcn_readlane((int)lo, 7)) & 8191;
    }
    __syncthreads();
    // write centroid coords once, from history
    for (int j = t; j < 1024; j += 512) {
        int ci = ch[j];
        float x = sx[ci], y = sy[ci], z = sz[ci];
        size_t o = (size_t)(b*1024 + j) * 3;
        nxyz[o] = x; nxyz[o+1] = y; nxyz[o+2] = z;
        out_nxyz[o] = x; out_nxyz[o+1] = y; out_nxyz[o+2] = z;
    }
}

// ---------------- Ball query: one wave per center ----------------
__global__ __launch_bounds__(256) void ballquery_kernel(const float* __restrict__ xyz,
                                                        const float* __restrict__ nxyz,
                                                        int* __restrict__ idxbuf) {
    const int wib = threadIdx.x >> 6;
    const int lane = threadIdx.x & 63;
    const int c = blockIdx.x * 4 + wib;        // center id in [0, 8192)
    const int b = c >> 10;
    const float* xb = xyz + (size_t)b * 8192 * 3;
    const float cx = nxyz[c*3+0], cy = nxyz[c*3+1], cz = nxyz[c*3+2];
    const float R2 = 0.04f;                    // valid iff !(sqr > R2)
    int count = 0, first = 0;
    int* ob = idxbuf + (size_t)c * 32;
    for (int base = 0; base < 8192; base += 64) {
        int i = base + lane;
        float dx = __fsub_rn(xb[i*3+0], cx);
        float dy = __fsub_rn(xb[i*3+1], cy);
        float dz = __fsub_rn(xb[i*3+2], cz);
        float sq = __fadd_rn(__fadd_rn(__fmul_rn(dx,dx), __fmul_rn(dy,dy)), __fmul_rn(dz,dz));
        bool pass = !(sq > R2);
        unsigned long long mask = __ballot(pass);
        if (count == 0 && mask) first = base + (int)__builtin_ctzll(mask);
        int pos = count + (int)__popcll(mask & ((1ull << lane) - 1ull));
        if (pass && pos < 32) ob[pos] = i;
        count += (int)__popcll(mask);
        if (count >= 32) break;
    }
    if (count < 32 && lane >= count && lane < 32) ob[lane] = first;
}

// ---------------- Layer 0: gather(67) @ w0(67x64) -> z0 bf16 + stats ----------------
__global__ __launch_bounds__(256) void layer0_kernel(
        const float* __restrict__ xyz, const float* __restrict__ points,
        const float* __restrict__ nxyz, const int* __restrict__ idxbuf,
        const float* __restrict__ w0, unsigned short* __restrict__ z0,
        float* __restrict__ stats0) {
    __shared__ float ws[67][64];
    __shared__ float xs[64][68];
    __shared__ float ssum[64], ssq[64];
    const int tid = threadIdx.x;
    for (int i = tid; i < 67*64; i += 256) ws[i>>6][i&63] = w0[i];
    if (tid < 64) { ssum[tid] = 0.f; ssq[tid] = 0.f; }
    const int rl = tid >> 2, tl = tid & 3;
    const int row = blockIdx.x * 64 + rl;
    const int b = row >> 15;
    const int s = (row >> 5) & 1023;
    const int gi = idxbuf[row];
    const float* pb = points + ((size_t)(b*8192 + gi)) * 64;
    for (int e = tl; e < 67; e += 4) {
        float v;
        if (e < 3) v = xyz[(size_t)(b*8192+gi)*3 + e] - nxyz[(size_t)(b*1024+s)*3 + e];
        else       v = pb[e-3];
        xs[rl][e] = v;
    }
    __syncthreads();
    float acc[16];
#pragma unroll
    for (int j = 0; j < 16; ++j) acc[j] = 0.f;
    for (int k = 0; k < 67; ++k) {
        float xv = xs[rl][k];
        const float* wr = &ws[k][tl*16];
#pragma unroll
        for (int j = 0; j < 16; ++j) acc[j] = fmaf(xv, wr[j], acc[j]);
    }
    uint4 u0, u1;
    u0.x = f2bf(acc[0])  | (f2bf(acc[1])  << 16);
    u0.y = f2bf(acc[2])  | (f2bf(acc[3])  << 16);
    u0.z = f2bf(acc[4])  | (f2bf(acc[5])  << 16);
    u0.w = f2bf(acc[6])  | (f2bf(acc[7])  << 16);
    u1.x = f2bf(acc[8])  | (f2bf(acc[9])  << 16);
    u1.y = f2bf(acc[10]) | (f2bf(acc[11]) << 16);
    u1.z = f2bf(acc[12]) | (f2bf(acc[13]) << 16);
    u1.w = f2bf(acc[14]) | (f2bf(acc[15]) << 16);
    uint4* zp = (uint4*)(z0 + (size_t)row * 64) + tl*2;
    zp[0] = u0; zp[1] = u1;
#pragma unroll
    for (int j = 0; j < 16; ++j) {
        atomicAdd(&ssum[tl*16+j], acc[j]);
        atomicAdd(&ssq[tl*16+j], acc[j]*acc[j]);
    }
    __syncthreads();
    if (tid < 64) {
        atomicAdd(&stats0[tid], ssum[tid]);
        atomicAdd(&stats0[64+tid], ssq[tid]);
    }
}

// ---------------- Layer 1: relu(bn0(z0)) @ w1(64x64) -> z1 bf16 + stats ----------------
__global__ __launch_bounds__(256) void layer1_kernel(
        const unsigned short* __restrict__ z0, const float* __restrict__ stats0,
        const float* __restrict__ gamma0, const float* __restrict__ beta0,
        const float* __restrict__ w1, unsigned short* __restrict__ z1,
        float* __restrict__ stats1) {
    __shared__ float ws[64][64];
    __shared__ float xs[64][68];
    __shared__ float scale[64], shift[64];
    __shared__ float ssum[64], ssq[64];
    const int tid = threadIdx.x;
    for (int i = tid; i < 64*64; i += 256) ws[i>>6][i&63] = w1[i];
    if (tid < 64) {
        float m = stats0[tid] * INV_CNT;
        float v = stats0[64+tid] * INV_CNT - m*m;
        float rs = rsqrtf(v + 1e-3f);
        float sc = gamma0[tid] * rs;
        scale[tid] = sc; shift[tid] = beta0[tid] - m*sc;
        ssum[tid] = 0.f; ssq[tid] = 0.f;
    }
    const int rl = tid >> 2, tl = tid & 3;
    const size_t row = (size_t)blockIdx.x * 64 + rl;
    const uint4* zr = (const uint4*)(z0 + row * 64) + tl*2;
    uint4 a = zr[0], bq = zr[1];
    float* xr = &xs[rl][tl*16];
    xr[0] = bf2f(a.x & 0xffffu);  xr[1] = bf2f(a.x >> 16);
    xr[2] = bf2f(a.y & 0xffffu);  xr[3] = bf2f(a.y >> 16);
    xr[4] = bf2f(a.z & 0xffffu);  xr[5] = bf2f(a.z >> 16);
    xr[6] = bf2f(a.w & 0xffffu);  xr[7] = bf2f(a.w >> 16);
    xr[8] = bf2f(bq.x & 0xffffu); xr[9] = bf2f(bq.x >> 16);
    xr[10] = bf2f(bq.y & 0xffffu); xr[11] = bf2f(bq.y >> 16);
    xr[12] = bf2f(bq.z & 0xffffu); xr[13] = bf2f(bq.z >> 16);
    xr[14] = bf2f(bq.w & 0xffffu); xr[15] = bf2f(bq.w >> 16);
    __syncthreads();     // scale ready + raw xs ready
#pragma unroll
    for (int j = 0; j < 16; ++j) {
        int e = tl*16 + j;
        xs[rl][e] = fmaxf(xs[rl][e]*scale[e] + shift[e], 0.f);
    }
    __syncthreads();
    float acc[16];
#pragma unroll
    for (int j = 0; j < 16; ++j) acc[j] = 0.f;
    for (int k = 0; k < 64; ++k) {
        float xv = xs[rl][k];
        const float* wr = &ws[k][tl*16];
#pragma unroll
        for (int j = 0; j < 16; ++j) acc[j] = fmaf(xv, wr[j], acc[j]);
    }
    uint4 u0, u1;
    u0.x = f2bf(acc[0])  | (f2bf(acc[1])  << 16);
    u0.y = f2bf(acc[2])  | (f2bf(acc[3])  << 16);
    u0.z = f2bf(acc[4])  | (f2bf(acc[5])  << 16);
    u0.w = f2bf(acc[6])  | (f2bf(acc[7])  << 16);
    u1.x = f2bf(acc[8])  | (f2bf(acc[9])  << 16);
    u1.y = f2bf(acc[10]) | (f2bf(acc[11]) << 16);
    u1.z = f2bf(acc[12]) | (f2bf(acc[13]) << 16);
    u1.w = f2bf(acc[14]) | (f2bf(acc[15]) << 16);
    uint4* zp = (uint4*)(z1 + row * 64) + tl*2;
    zp[0] = u0; zp[1] = u1;
#pragma unroll
    for (int j = 0; j < 16; ++j) {
        atomicAdd(&ssum[tl*16+j], acc[j]);
        atomicAdd(&ssq[tl*16+j], acc[j]*acc[j]);
    }
    __syncthreads();
    if (tid < 64) {
        atomicAdd(&stats1[tid], ssum[tid]);
        atomicAdd(&stats1[64+tid], ssq[tid]);
    }
}

// ------- Layer 2: relu(bn1(z1)) @ w2(64x128); store per-(b,s) channel max + stats -------
__global__ __launch_bounds__(256) void layer2_kernel(
        const unsigned short* __restrict__ z1, const float* __restrict__ stats1,
        const float* __restrict__ gamma1, const float* __restrict__ beta1,
        const float* __restrict__ w2, float* __restrict__ maxz2,
        float* __restrict__ stats2) {
    __shared__ float ws[64][128];
    __shared__ float xs[32][68];
    __shared__ float scale[64], shift[64];
    __shared__ float ssum[128], ssq[128];
    __shared__ float mx[4][128];
    const int tid = threadIdx.x;
    for (int i = tid; i < 64*128; i += 256) ws[i>>7][i&127] = w2[i];
    if (tid < 64) {
        float m = stats1[tid] * INV_CNT;
        float v = stats1[64+tid] * INV_CNT - m*m;
        float rs = rsqrtf(v + 1e-3f);
        float sc = gamma1[tid] * rs;
        scale[tid] = sc; shift[tid] = beta1[tid] - m*sc;
    }
    if (tid < 128) { ssum[tid] = 0.f; ssq[tid] = 0.f; }
    const int kr = tid >> 3, cg = tid & 7;     // kr: sample k in [0,32), cg: 16-channel group
    const size_t row = (size_t)blockIdx.x * 32 + kr;
    const uint4* zr = (const uint4*)(z1 + row * 64) + cg;
    uint4 a = zr[0];
    float* xr = &xs[kr][cg*8];
    xr[0] = bf2f(a.x & 0xffffu); xr[1] = bf2f(a.x >> 16);
    xr[2] = bf2f(a.y & 0xffffu); xr[3] = bf2f(a.y >> 16);
    xr[4] = bf2f(a.z & 0xffffu); xr[5] = bf2f(a.z >> 16);
    xr[6] = bf2f(a.w & 0xffffu); xr[7] = bf2f(a.w >> 16);
    __syncthreads();
#pragma unroll
    for (int j = 0; j < 8; ++j) {
        int e = cg*8 + j;
        xs[kr][e] = fmaxf(xs[kr][e]*scale[e] + shift[e], 0.f);
    }
    __syncthreads();
    float acc[16];
#pragma unroll
    for (int j = 0; j < 16; ++j) acc[j] = 0.f;
    for (int k = 0; k < 64; ++k) {
        float xv = xs[kr][k];
        const float* wr = &ws[k][cg*16];
#pragma unroll
        for (int j = 0; j < 16; ++j) acc[j] = fmaf(xv, wr[j], acc[j]);
    }
#pragma unroll
    for (int j = 0; j < 16; ++j) {
        atomicAdd(&ssum[cg*16+j], acc[j]);
        atomicAdd(&ssq[cg*16+j], acc[j]*acc[j]);
    }
    // max over k: shuffle (lanes with same cg are stride-8), then cross-wave via LDS
#pragma unroll
    for (int off = 32; off >= 8; off >>= 1) {
#pragma unroll
        for (int j = 0; j < 16; ++j) {
            float ov = __shfl_down(acc[j], off);
            acc[j] = fmaxf(acc[j], ov);
        }
    }
    const int wv = tid >> 6, ln = tid & 63;
    if (ln < 8) {
#pragma unroll
        for (int j = 0; j < 16; ++j) mx[wv][ln*16+j] = acc[j];
    }
    __syncthreads();
    if (tid < 128) {
        float m = fmaxf(fmaxf(mx[0][tid], mx[1][tid]), fmaxf(mx[2][tid], mx[3][tid]));
        maxz2[(size_t)blockIdx.x * 128 + tid] = m;
        atomicAdd(&stats2[tid], ssum[tid]);
        atomicAdd(&stats2[128+tid], ssq[tid]);
    }
}

// ---------------- Final: out = relu(bn2(maxz2)) ----------------
__global__ __launch_bounds__(256) void final_kernel(
        const float* __restrict__ maxz2, const float* __restrict__ stats2,
        const float* __restrict__ gamma2, const float* __restrict__ beta2,
        float* __restrict__ out) {
    const int i = blockIdx.x * 256 + threadIdx.x;    // over 8*1024*128
    const int f = i & 127;
    float m = stats2[f] * INV_CNT;
    float v = stats2[128+f] * INV_CNT - m*m;
    float rs = rsqrtf(v + 1e-3f);
    out[24576 + i] = fmaxf(gamma2[f]*((maxz2[i]-m)*rs) + beta2[f], 0.f);
}

extern "C" void kernel_launch(void* const* d_in, const int* in_sizes, int n_in,
                              void* d_out, int out_size, void* d_ws, size_t ws_size,
                              hipStream_t stream) {
    const float* xyz    = (const float*)d_in[0];
    const float* points = (const float*)d_in[1];
    const float* w0     = (const float*)d_in[2];
    const float* g0     = (const float*)d_in[3];
    const float* b0     = (const float*)d_in[4];
    const float* w1     = (const float*)d_in[5];
    const float* g1     = (const float*)d_in[6];
    const float* b1     = (const float*)d_in[7];
    const float* w2     = (const float*)d_in[8];
    const float* g2     = (const float*)d_in[9];
    const float* b2     = (const float*)d_in[10];
    float* out = (float*)d_out;
    char* ws = (char*)d_ws;

    // workspace layout (bytes), all 256-aligned:
    float* nxyz            = (float*)(ws + 0);          // 24576 f32   = 98304 B
    int*   idxbuf          = (int*)  (ws + 98304);      // 262144 i32  = 1048576 B
    float* stats           = (float*)(ws + 1146880);    // 512 f32 (s0:128, s1:128, s2:256)
    unsigned short* z0     = (unsigned short*)(ws + 1148928);   // 32 MB bf16
    unsigned short* z1     = (unsigned short*)(ws + 34703360);  // 32 MB bf16
    float* maxz2           = (float*)(ws + 68257792);   // 4 MB f32
    // total ~72.5 MB

    hipMemsetAsync(stats, 0, 512 * sizeof(float), stream);
    fps_kernel<<<8, 512, 0, stream>>>(xyz, nxyz, out);
    ballquery_kernel<<<2048, 256, 0, stream>>>(xyz, nxyz, idxbuf);
    layer0_kernel<<<4096, 256, 0, stream>>>(xyz, points, nxyz, idxbuf, w0, z0, stats);
    layer1_kernel<<<4096, 256, 0, stream>>>(z0, stats, g0, b0, w1, z1, stats + 128);
    layer2_kernel<<<8192, 256, 0, stream>>>(z1, stats + 128, g1, b1, w2, maxz2, stats + 256);
    final_kernel<<<4096, 256, 0, stream>>>(maxz2, stats + 256, g2, b2, out);
}